// Round 5
// baseline (3463.443 us; speedup 1.0000x reference)
//
#include <hip/hip_runtime.h>
#include <math.h>

// ---------------- problem constants ----------------
#define NB 16
#define TT 12
#define H1 47
#define W1D 46
#define H2 46
#define W2D 44

#define H1N (NB * H1 * W1D * 32)   // 1106944
#define H2N (NB * H2 * W2D * 32)   // 1036288
#define SLF 32
#define SLB 8192
#define SPAN1 (SLF + H1N + SLB)    // 1115168
#define SPAN2 (SLF + H2N + SLB)    // 1044512
#define NBLK 576

typedef short short8v __attribute__((ext_vector_type(8)));
typedef float floatx4 __attribute__((ext_vector_type(4)));

__device__ __forceinline__ short f2bf(float x) {
    unsigned u = __float_as_uint(x);
    u = (u + 0x7FFFu + ((u >> 16) & 1u)) >> 16;   // RNE
    return (short)u;
}
__device__ __forceinline__ float bf2f(short s) {
    return __uint_as_float(((unsigned)(unsigned short)s) << 16);
}
__device__ __forceinline__ float hsig(float z) {
    return fminf(fmaxf(0.2f * z + 0.5f, 0.f), 1.f);
}

// Device-scope grid barrier: one counter per use (zeroed by host-side
// hipMemsetAsync each launch). All NBLK blocks must be co-resident:
// guaranteed by __launch_bounds__(256,3) -> 3 blocks/CU -> 768 >= 576.
__device__ __forceinline__ void gbar(int* bar, int nb) {
    __syncthreads();
    if (threadIdx.x == 0) {
        __threadfence();
        __hip_atomic_fetch_add(bar, 1, __ATOMIC_ACQ_REL, __HIP_MEMORY_SCOPE_AGENT);
        while (__hip_atomic_load(bar, __ATOMIC_ACQUIRE, __HIP_MEMORY_SCOPE_AGENT) < nb)
            __builtin_amdgcn_s_sleep(2);
        __threadfence();
    }
    __syncthreads();
}

// ---------------------------------------------------------------------------
// One ConvLSTM timestep body (identical math to R3, which passed).
// Cell state lives in registers (block owns its tile for all timesteps).
// Block tile 8x16 (M=128), N=128; 4 waves = (mhalf, fh); wave M=64, N=64.
// ---------------------------------------------------------------------------
template<int LAYER>
__device__ __forceinline__ void step_body(
    const short* __restrict__ xin,     // L1: xbf + t*6912 ; L2: h1 current
    const short* __restrict__ hprev,
    const short* __restrict__ Bt,
    short* __restrict__ hnext,
    short* __restrict__ pool, int t2,
    int b, int y0, int x0, short* xim,
    float (&creg)[4][4],
    float bi, float bfv, float bcv, float bov)
{
    constexpr int Ho   = (LAYER == 1) ? H1 : H2;
    constexpr int Wo   = (LAYER == 1) ? W1D : W2D;
    constexpr int NCH  = (LAYER == 1) ? 7 : 12;
    constexpr int REC0 = (LAYER == 1) ? 1 : 6;
    constexpr int IW   = (LAYER == 1) ? 48 : W1D;
    constexpr int IBS  = (LAYER == 1) ? (TT * 48 * 48 * 3) : (H1 * W1D * 32);
    constexpr int HBS  = Ho * Wo * 32;

    const int tid = threadIdx.x;
    const int lane = tid & 63, w = tid >> 6;
    const int mhalf = w >> 1, fh = w & 1;
    const int tx = lane & 15, q = lane >> 4;

    if (LAYER == 1) {
        // padded im2col chunk: m=0..127 (8x16 tile), k=kk*3+cc (18 -> pad 32)
        for (int i = tid; i < 128 * 32; i += 256) {
            int m = i >> 5, k = i & 31;
            short v = 0;
            if (k < 18) {
                int kk = k / 3, cc = k - kk * 3;
                int ky = (kk >= 3) ? 1 : 0, kx = kk - ky * 3;
                int ys = y0 + (m >> 4) + ky; if (ys > 47) ys = 47;
                int xs = x0 + (m & 15) + kx; if (xs > 47) xs = 47;
                v = xin[b * IBS + (ys * 48 + xs) * 3 + cc];
            }
            xim[m * 40 + k] = v;
        }
        __syncthreads();
    }

    int base_in[4], base_rc[4];
    bool okYr[4][2];
#pragma unroll
    for (int a = 0; a < 4; ++a) {
        int y = y0 + mhalf * 4 + a;
        base_in[a] = b * IBS + (y * IW + (x0 + tx)) * 32 + q * 8;
        base_rc[a] = b * HBS + (y * Wo + (x0 + tx - 1)) * 32 + q * 8;
        okYr[a][0] = y < Ho;
        okYr[a][1] = (y + 1) < Ho;
    }
    bool okX[3];
#pragma unroll
    for (int kx = 0; kx < 3; ++kx)
        okX[kx] = (unsigned)(x0 + tx - 1 + kx) < (unsigned)Wo;

    const short* Btl = Bt + fh * 2048 + tx * 32 + q * 8;
    floatx4 acc[4][4] = {};
    const short8v z8 = (short8v)0;

#pragma unroll
    for (int c = 0; c < NCH; ++c) {
        short8v bf4[4], af[4];
#pragma unroll
        for (int g = 0; g < 4; ++g)
            bf4[g] = *(const short8v*)(Btl + c * 4096 + g * 512);

        if (LAYER == 1 && c == 0) {
#pragma unroll
            for (int a = 0; a < 4; ++a)
                af[a] = *(const short8v*)&xim[((mhalf * 4 + a) * 16 + tx) * 40 + q * 8];
        } else if (LAYER == 2 && c < REC0) {
            int ky = (c >= 3) ? 1 : 0, kx = c - ky * 3;
#pragma unroll
            for (int a = 0; a < 4; ++a)
                af[a] = *(const short8v*)(xin + base_in[a] + (ky * IW + kx) * 32);
        } else {
            int kk = c - REC0;
            int ky = (kk >= 3) ? 1 : 0, kx = kk - ky * 3;
#pragma unroll
            for (int a = 0; a < 4; ++a) {
                short8v v = *(const short8v*)(hprev + base_rc[a] + (ky * Wo + kx) * 32);
                af[a] = (okYr[a][ky] && okX[kx]) ? v : z8;
            }
        }
#pragma unroll
        for (int a = 0; a < 4; ++a)
#pragma unroll
            for (int g = 0; g < 4; ++g)
                acc[a][g] = __builtin_amdgcn_mfma_f32_16x16x32_bf16(af[a], bf4[g], acc[a][g], 0, 0, 0);
    }

    const int f = fh * 16 + tx;
    float hv[4][4];
#pragma unroll
    for (int a = 0; a < 4; ++a) {
        int y = y0 + mhalf * 4 + a;
        bool yok = y < Ho;
#pragma unroll
        for (int r = 0; r < 4; ++r) {
            int xe = x0 + q * 4 + r;
            float hn = 0.f;
            if (yok && xe < Wo) {
                int o = b * HBS + (y * Wo + xe) * 32 + f;
                float ig = hsig(acc[a][0][r] + bi);
                float fg = hsig(acc[a][1][r] + bfv);
                float gg = fmaxf(acc[a][2][r] + bcv, 0.f);
                float og = hsig(acc[a][3][r] + bov);
                float cn = fg * creg[a][r] + ig * gg;
                creg[a][r] = cn;
                short hb = f2bf(og * fmaxf(cn, 0.f));
                hnext[o] = hb;
                hn = bf2f(hb);
            }
            hv[a][r] = hn;
        }
    }

    if (LAYER == 2) {
#pragma unroll
        for (int ap = 0; ap < 2; ++ap) {
            int py = y0 / 2 + mhalf * 2 + ap;
#pragma unroll
            for (int rp = 0; rp < 2; ++rp) {
                int px = x0 / 2 + q * 2 + rp;
                if (py < 23 && px < 22) {
                    float m = fmaxf(fmaxf(hv[2 * ap][2 * rp],     hv[2 * ap][2 * rp + 1]),
                                    fmaxf(hv[2 * ap + 1][2 * rp], hv[2 * ap + 1][2 * rp + 1]));
                    pool[(size_t)b * 194304 + ((t2 * 23 + py) * 22 + px) * 32 + f] = f2bf(m);
                }
            }
        }
    }
}

// ---------------------------------------------------------------------------
// Single persistent kernel (manual grid barrier): init -> 13 pipelined steps
// -> gemv -> final dense. 576 blocks: 0..287 L1, 288..575 L2.
// ---------------------------------------------------------------------------
__global__ __launch_bounds__(256, 3) void persist(
    const float* __restrict__ x,
    const float* __restrict__ W1s, const float* __restrict__ U1s, const float* __restrict__ b1,
    const float* __restrict__ W2s, const float* __restrict__ U2s, const float* __restrict__ b2,
    const float* __restrict__ Wd1, const float* __restrict__ bd1,
    const float* __restrict__ Wd2, const float* __restrict__ bd2,
    float* __restrict__ out, short* __restrict__ wsb, int* __restrict__ bar)
{
    short* Bt1 = wsb;                 // 28672
    short* Bt2 = Bt1 + 28672;         // 49152
    short* xbf = Bt2 + 49152;         // 1327104
    short* p   = xbf + 1327104;       // 3108864
    short* zr  = p + 3108864;         // zero region: h buffers + d1
    short* h1buf[2] = { zr + SLF, zr + SPAN1 + SLF };
    short* h2buf[2] = { zr + 2 * SPAN1 + SLF, zr + 2 * SPAN1 + SPAN2 + SLF };
    float* d1 = (float*)(zr + 2 * SPAN1 + 2 * SPAN2);   // 160 floats

    const int gid = blockIdx.x;
    const int tid = threadIdx.x;
    const int gtid = gid * 256 + tid;
    const int gthreads = NBLK * 256;
    int barn = 0;

    // ---- init: zero h/d1, convert x, transform weights ----
    {
        int4* zp = (int4*)zr;
        const int nz = ((2 * SPAN1 + 2 * SPAN2) * 2 + 160 * 4) / 16;
        int4 z4; z4.x = z4.y = z4.z = z4.w = 0;
        for (int i = gtid; i < nz; i += gthreads) zp[i] = z4;
        for (int i = gtid; i < 1327104; i += gthreads) xbf[i] = f2bf(x[i]);
        for (int idx = gtid; idx < 77824; idx += gthreads) {
            int layer2 = idx >= 28672;
            int i = layer2 ? idx - 28672 : idx;
            int ci = i & 31, j = (i >> 5) & 15, g = (i >> 9) & 3, fh = (i >> 11) & 1, c = i >> 12;
            int col = g * 32 + fh * 16 + j;
            float v = 0.f;
            if (!layer2) {
                if (c == 0) {
                    if (ci < 18) { int kk = ci / 3, cc = ci - kk * 3; v = W1s[(kk * 3 + cc) * 128 + col]; }
                } else v = U1s[((c - 1) * 32 + ci) * 128 + col];
            } else {
                if (c < 6) v = W2s[(c * 32 + ci) * 128 + col];
                else       v = U2s[((c - 6) * 32 + ci) * 128 + col];
            }
            (layer2 ? Bt2 : Bt1)[i] = f2bf(v);
        }
    }
    gbar(bar + barn++, NBLK);

    // ---- persistent tile geometry ----
    const int layer = (gid >= 288) ? 1 : 0;
    const int rr = gid - layer * 288;
    const int b = rr / 18;
    const int tile = rr % 18;
    const int y0 = (tile / 3) * 8;
    const int x0 = (tile % 3) * 16;

    const int lane = tid & 63, w = tid >> 6;
    const int fh = w & 1;
    const int f = fh * 16 + (lane & 15);
    const float* bias = layer ? b2 : b1;
    const float bi = bias[f], bfv = bias[32 + f], bcv = bias[64 + f], bov = bias[96 + f];

    float creg[4][4];
#pragma unroll
    for (int a = 0; a < 4; ++a)
#pragma unroll
        for (int r = 0; r < 4; ++r) creg[a][r] = 0.f;

    __shared__ short xim[128 * 40];

    // ---- pipelined recurrence: step s runs L1(t=s) and L2(t=s-1) ----
    for (int s = 0; s <= TT; ++s) {
        if (layer == 0) {
            if (s < TT)
                step_body<1>(xbf + s * 6912, h1buf[(s + 1) & 1], Bt1,
                             h1buf[s & 1], nullptr, 0,
                             b, y0, x0, xim, creg, bi, bfv, bcv, bov);
        } else {
            if (s >= 1)
                step_body<2>(h1buf[(s + 1) & 1], h2buf[s & 1], Bt2,
                             h2buf[(s + 1) & 1], p, s - 1,
                             b, y0, x0, xim, creg, bi, bfv, bcv, bov);
        }
        gbar(bar + barn++, NBLK);
    }

    // ---- gemv: d1[b][j] += sum_k p[b][k] * Wd1[k][j] (blocks 0..255) ----
    if (gid < 256) {
        int by = gid >> 6;                 // batch group 4*by..4*by+3
        int k0 = (gid & 63) * 3036;        // 194304/64
        float part[4][10];
#pragma unroll
        for (int bb = 0; bb < 4; bb++)
#pragma unroll
            for (int j = 0; j < 10; j++) part[bb][j] = 0.f;

        for (int k = k0 + tid; k < k0 + 3036; k += 256) {
            const float* wr = Wd1 + (size_t)k * 10;
            float wv[10];
#pragma unroll
            for (int j = 0; j < 10; j++) wv[j] = wr[j];
#pragma unroll
            for (int bb = 0; bb < 4; bb++) {
                float m = bf2f(p[(size_t)(by * 4 + bb) * 194304 + k]);
#pragma unroll
                for (int j = 0; j < 10; j++) part[bb][j] = fmaf(m, wv[j], part[bb][j]);
            }
        }
        __shared__ float red[4][10][4];
        int ln = tid & 63, wv2 = tid >> 6;
#pragma unroll
        for (int bb = 0; bb < 4; bb++)
#pragma unroll
            for (int j = 0; j < 10; j++) {
                float v = part[bb][j];
                for (int off = 32; off > 0; off >>= 1) v += __shfl_down(v, off);
                if (ln == 0) red[bb][j][wv2] = v;
            }
        __syncthreads();
        if (tid < 40) {
            int bb = tid / 10, j = tid % 10;
            float s2 = red[bb][j][0] + red[bb][j][1] + red[bb][j][2] + red[bb][j][3];
            atomicAdd(&d1[(by * 4 + bb) * 10 + j], s2);
        }
    }
    gbar(bar + barn++, NBLK);

    // ---- final dense ----
    if (gid == 0 && tid < NB) {
        float s2 = bd2[0];
#pragma unroll
        for (int j = 0; j < 10; j++) s2 += (d1[tid * 10 + j] + bd1[j]) * Wd2[j];
        out[tid] = s2;
    }
}

// ---------------------------------------------------------------------------
extern "C" void kernel_launch(void* const* d_in, const int* in_sizes, int n_in,
                              void* d_out, int out_size, void* d_ws, size_t ws_size,
                              hipStream_t stream)
{
    const float* x   = (const float*)d_in[0];
    const float* W1s = (const float*)d_in[1];
    const float* U1s = (const float*)d_in[2];
    const float* b1  = (const float*)d_in[3];
    const float* W2s = (const float*)d_in[4];
    const float* U2s = (const float*)d_in[5];
    const float* b2  = (const float*)d_in[6];
    const float* Wd1 = (const float*)d_in[7];
    const float* bd1 = (const float*)d_in[8];
    const float* Wd2 = (const float*)d_in[9];
    const float* bd2 = (const float*)d_in[10];
    float* out = (float*)d_out;
    short* wsb = (short*)d_ws;

    // barrier counters after all data regions (64B-aligned), zeroed per launch
    // total data shorts: 4513792 + 4319360 + 320 = 8833472
    int* bar = (int*)((char*)d_ws + ((8833472 * 2 + 63) & ~63));
    hipMemsetAsync(bar, 0, 32 * sizeof(int), stream);

    persist<<<NBLK, 256, 0, stream>>>(
        x, W1s, U1s, b1, W2s, U2s, b2, Wd1, bd1, Wd2, bd2, out, wsb, bar);
}

// Round 6
// 392.529 us; speedup vs baseline: 8.8234x; 8.8234x over previous
//
#include <hip/hip_runtime.h>
#include <math.h>

// ---------------- problem constants ----------------
#define NB 16
#define TT 12
#define H1 47
#define W1D 46
#define H2 46
#define W2D 44

typedef short short8v __attribute__((ext_vector_type(8)));
typedef float floatx4 __attribute__((ext_vector_type(4)));

__device__ __forceinline__ short f2bf(float x) {
    unsigned u = __float_as_uint(x);
    u = (u + 0x7FFFu + ((u >> 16) & 1u)) >> 16;   // RNE
    return (short)u;
}
__device__ __forceinline__ float bf2f(short s) {
    return __uint_as_float(((unsigned)(unsigned short)s) << 16);
}
__device__ __forceinline__ float hsig(float z) {
    return fminf(fmaxf(0.2f * z + 0.5f, 0.f), 1.f);
}

// ---------------------------------------------------------------------------
__global__ __launch_bounds__(256) void convert_x(const float* __restrict__ x,
                                                 short* __restrict__ xbf, int n) {
    int i = blockIdx.x * 256 + threadIdx.x;
    if (i < n) xbf[i] = f2bf(x[i]);
}

// ---------------------------------------------------------------------------
// Weights -> MFMA B-fragment layout, bf16 (same as R2/R3).
// flat idx = ((c*2+fh)*4+g)*512 + j*32 + ci ; column = g*32+fh*16+j, k = ci
// ---------------------------------------------------------------------------
__global__ __launch_bounds__(256) void transform_w(
    const float* __restrict__ W1s, const float* __restrict__ U1s,
    const float* __restrict__ W2s, const float* __restrict__ U2s,
    short* __restrict__ Bt1, short* __restrict__ Bt2)
{
    int idx = blockIdx.x * 256 + threadIdx.x;       // 0..77823
    int layer2 = idx >= 28672;
    int i = layer2 ? idx - 28672 : idx;
    int ci = i & 31, j = (i >> 5) & 15, g = (i >> 9) & 3, fh = (i >> 11) & 1, c = i >> 12;
    int col = g * 32 + fh * 16 + j;
    float v = 0.f;
    if (!layer2) {
        if (c == 0) {
            if (ci < 18) { int kk = ci / 3, cc = ci - kk * 3; v = W1s[(kk * 3 + cc) * 128 + col]; }
        } else {
            v = U1s[((c - 1) * 32 + ci) * 128 + col];
        }
    } else {
        if (c < 6) v = W2s[(c * 32 + ci) * 128 + col];
        else       v = U2s[((c - 6) * 32 + ci) * 128 + col];
    }
    (layer2 ? Bt2 : Bt1)[i] = f2bf(v);
}

// ---------------------------------------------------------------------------
// One ConvLSTM timestep body (identical math to R3, which passed).
// Block tile 8x16 (M=128), N=128; 4 waves = (mhalf, fh); wave M=64, N=64.
// ---------------------------------------------------------------------------
template<int LAYER>
__device__ __forceinline__ void step_body(
    const short* __restrict__ xin,
    const short* __restrict__ hprev,
    const short* __restrict__ Bt,
    const float* __restrict__ bias,
    float* __restrict__ cst,
    short* __restrict__ hnext,
    short* __restrict__ pool, int t2, int b, int y0, int x0, short* xim)
{
    constexpr int Ho   = (LAYER == 1) ? H1 : H2;
    constexpr int Wo   = (LAYER == 1) ? W1D : W2D;
    constexpr int NCH  = (LAYER == 1) ? 7 : 12;
    constexpr int REC0 = (LAYER == 1) ? 1 : 6;
    constexpr int IW   = (LAYER == 1) ? 48 : W1D;
    constexpr int IBS  = (LAYER == 1) ? (TT * 48 * 48 * 3) : (H1 * W1D * 32);
    constexpr int HBS  = Ho * Wo * 32;

    const int tid = threadIdx.x;
    const int lane = tid & 63, w = tid >> 6;
    const int mhalf = w >> 1, fh = w & 1;
    const int tx = lane & 15, q = lane >> 4;

    if (LAYER == 1) {
        // padded im2col chunk: m=0..127 (8x16 tile), k=kk*3+cc (18 -> pad 32)
        for (int i = tid; i < 128 * 32; i += 256) {
            int m = i >> 5, k = i & 31;
            short v = 0;
            if (k < 18) {
                int kk = k / 3, cc = k - kk * 3;
                int ky = (kk >= 3) ? 1 : 0, kx = kk - ky * 3;
                int ys = y0 + (m >> 4) + ky; if (ys > 47) ys = 47;
                int xs = x0 + (m & 15) + kx; if (xs > 47) xs = 47;
                v = xin[b * IBS + (ys * 48 + xs) * 3 + cc];
            }
            xim[m * 40 + k] = v;
        }
        __syncthreads();
    }

    int base_in[4], base_rc[4];
    bool okYr[4][2];
#pragma unroll
    for (int a = 0; a < 4; ++a) {
        int y = y0 + mhalf * 4 + a;
        base_in[a] = b * IBS + (y * IW + (x0 + tx)) * 32 + q * 8;
        base_rc[a] = b * HBS + (y * Wo + (x0 + tx - 1)) * 32 + q * 8;
        okYr[a][0] = y < Ho;
        okYr[a][1] = (y + 1) < Ho;
    }
    bool okX[3];
#pragma unroll
    for (int kx = 0; kx < 3; ++kx)
        okX[kx] = (unsigned)(x0 + tx - 1 + kx) < (unsigned)Wo;

    const short* Btl = Bt + fh * 2048 + tx * 32 + q * 8;
    floatx4 acc[4][4] = {};
    const short8v z8 = (short8v)0;

#pragma unroll
    for (int c = 0; c < NCH; ++c) {
        short8v bf4[4], af[4];
#pragma unroll
        for (int g = 0; g < 4; ++g)
            bf4[g] = *(const short8v*)(Btl + c * 4096 + g * 512);

        if (LAYER == 1 && c == 0) {
#pragma unroll
            for (int a = 0; a < 4; ++a)
                af[a] = *(const short8v*)&xim[((mhalf * 4 + a) * 16 + tx) * 40 + q * 8];
        } else if (LAYER == 2 && c < REC0) {
            int ky = (c >= 3) ? 1 : 0, kx = c - ky * 3;
#pragma unroll
            for (int a = 0; a < 4; ++a)
                af[a] = *(const short8v*)(xin + base_in[a] + (ky * IW + kx) * 32);
        } else {
            int kk = c - REC0;
            int ky = (kk >= 3) ? 1 : 0, kx = kk - ky * 3;
#pragma unroll
            for (int a = 0; a < 4; ++a) {
                short8v v = *(const short8v*)(hprev + base_rc[a] + (ky * Wo + kx) * 32);
                af[a] = (okYr[a][ky] && okX[kx]) ? v : z8;
            }
        }
#pragma unroll
        for (int a = 0; a < 4; ++a)
#pragma unroll
            for (int g = 0; g < 4; ++g)
                acc[a][g] = __builtin_amdgcn_mfma_f32_16x16x32_bf16(af[a], bf4[g], acc[a][g], 0, 0, 0);
    }

    const int f = fh * 16 + tx;
    const float bi = bias[f], bfv = bias[32 + f], bcv = bias[64 + f], bov = bias[96 + f];
    float hv[4][4];
#pragma unroll
    for (int a = 0; a < 4; ++a) {
        int y = y0 + mhalf * 4 + a;
        bool yok = y < Ho;
#pragma unroll
        for (int r = 0; r < 4; ++r) {
            int xe = x0 + q * 4 + r;
            float hn = 0.f;
            if (yok && xe < Wo) {
                int o = b * HBS + (y * Wo + xe) * 32 + f;
                float ig = hsig(acc[a][0][r] + bi);
                float fg = hsig(acc[a][1][r] + bfv);
                float gg = fmaxf(acc[a][2][r] + bcv, 0.f);
                float og = hsig(acc[a][3][r] + bov);
                float cn = fg * cst[o] + ig * gg;
                cst[o] = cn;
                short hb = f2bf(og * fmaxf(cn, 0.f));
                hnext[o] = hb;
                hn = bf2f(hb);
            }
            hv[a][r] = hn;
        }
    }

    if (LAYER == 2) {
#pragma unroll
        for (int ap = 0; ap < 2; ++ap) {
            int py = y0 / 2 + mhalf * 2 + ap;
#pragma unroll
            for (int rp = 0; rp < 2; ++rp) {
                int px = x0 / 2 + q * 2 + rp;
                if (py < 23 && px < 22) {
                    float m = fmaxf(fmaxf(hv[2 * ap][2 * rp],     hv[2 * ap][2 * rp + 1]),
                                    fmaxf(hv[2 * ap + 1][2 * rp], hv[2 * ap + 1][2 * rp + 1]));
                    pool[(size_t)b * 194304 + ((t2 * 23 + py) * 22 + px) * 32 + f] = f2bf(m);
                }
            }
        }
    }
}

// ---------------------------------------------------------------------------
// Fused pipeline step with XCD-locality swizzle.
// grid = 576 (1-D). Assumed XCD = blockIdx.x % 8 (speed heuristic only):
// XCD k owns batches {2k, 2k+1}, both layers -> per-XCD working set
// (h1,h2,c1,c2 slices + weights) ~1.8 MB, fits the 4 MiB XCD L2.
// ---------------------------------------------------------------------------
__global__ __launch_bounds__(256, 2) void fused_step(
    const short* __restrict__ xt,
    const short* __restrict__ h1r, short* __restrict__ h1w,
    const short* __restrict__ h2r, short* __restrict__ h2w,
    const short* __restrict__ Bt1, const short* __restrict__ Bt2,
    const float* __restrict__ b1, const float* __restrict__ b2,
    float* __restrict__ c1, float* __restrict__ c2,
    short* __restrict__ pool, int t2, int do1, int do2)
{
    __shared__ short xim[128 * 40];
    int gid  = blockIdx.x;
    int xcd  = gid & 7;
    int r    = gid >> 3;          // 0..71
    int layer = r & 1;
    int bpar  = (r >> 1) & 1;
    int tile  = r >> 2;           // 0..17
    int b  = xcd * 2 + bpar;
    int y0 = (tile / 3) * 8;
    int x0 = (tile % 3) * 16;

    if (layer == 0) {
        if (!do1) return;
        step_body<1>(xt, h1r, Bt1, b1, c1, h1w, nullptr, 0, b, y0, x0, xim);
    } else {
        if (!do2) return;
        step_body<2>(h1r, h2r, Bt2, b2, c2, h2w, pool, t2, b, y0, x0, xim);
    }
}

// ---------------------------------------------------------------------------
__global__ __launch_bounds__(256) void gemv_kernel(
    const short* __restrict__ p, const float* __restrict__ Wd1, float* __restrict__ d1)
{
    int by = blockIdx.y;                 // batch group: 4*by .. 4*by+3
    int k0 = blockIdx.x * 3036;          // 194304 / 64
    float part[4][10];
#pragma unroll
    for (int bb = 0; bb < 4; bb++)
#pragma unroll
        for (int j = 0; j < 10; j++) part[bb][j] = 0.f;

    for (int k = k0 + threadIdx.x; k < k0 + 3036; k += 256) {
        const float* wr = Wd1 + (size_t)k * 10;
        float wv[10];
#pragma unroll
        for (int j = 0; j < 10; j++) wv[j] = wr[j];
#pragma unroll
        for (int bb = 0; bb < 4; bb++) {
            float m = bf2f(p[(size_t)(by * 4 + bb) * 194304 + k]);
#pragma unroll
            for (int j = 0; j < 10; j++) part[bb][j] = fmaf(m, wv[j], part[bb][j]);
        }
    }
    __shared__ float red[4][10][4];
    int lane = threadIdx.x & 63, wv2 = threadIdx.x >> 6;
#pragma unroll
    for (int bb = 0; bb < 4; bb++)
#pragma unroll
        for (int j = 0; j < 10; j++) {
            float v = part[bb][j];
            for (int off = 32; off > 0; off >>= 1) v += __shfl_down(v, off);
            if (lane == 0) red[bb][j][wv2] = v;
        }
    __syncthreads();
    if (threadIdx.x < 40) {
        int bb = threadIdx.x / 10, j = threadIdx.x % 10;
        float s = red[bb][j][0] + red[bb][j][1] + red[bb][j][2] + red[bb][j][3];
        atomicAdd(&d1[(by * 4 + bb) * 10 + j], s);
    }
}

__global__ void final_dense(const float* __restrict__ d1, const float* __restrict__ bd1,
                            const float* __restrict__ Wd2, const float* __restrict__ bd2,
                            float* __restrict__ out)
{
    int b = threadIdx.x;
    if (b < NB) {
        float s = bd2[0];
#pragma unroll
        for (int j = 0; j < 10; j++) s += (d1[b * 10 + j] + bd1[j]) * Wd2[j];
        out[b] = s;
    }
}

// ---------------------------------------------------------------------------
extern "C" void kernel_launch(void* const* d_in, const int* in_sizes, int n_in,
                              void* d_out, int out_size, void* d_ws, size_t ws_size,
                              hipStream_t stream)
{
    const float* x   = (const float*)d_in[0];
    const float* W1s = (const float*)d_in[1];
    const float* U1s = (const float*)d_in[2];
    const float* b1  = (const float*)d_in[3];
    const float* W2s = (const float*)d_in[4];
    const float* U2s = (const float*)d_in[5];
    const float* b2  = (const float*)d_in[6];
    const float* Wd1 = (const float*)d_in[7];
    const float* bd1 = (const float*)d_in[8];
    const float* Wd2 = (const float*)d_in[9];
    const float* bd2 = (const float*)d_in[10];
    float* out = (float*)d_out;

    const int H1N = NB * H1 * W1D * 32;   // 1106944
    const int H2N = NB * H2 * W2D * 32;   // 1036288
    const int SLF = 32, SLB = 8192;
    const int SPAN1 = SLF + H1N + SLB;
    const int SPAN2 = SLF + H2N + SLB;

    short* Bt1 = (short*)d_ws;            // 28672
    short* Bt2 = Bt1 + 28672;             // 49152
    short* xbf = Bt2 + 49152;             // 1327104
    short* p   = xbf + 1327104;           // 3108864
    short* zr  = p + 3108864;             // ---- zero region ----
    short* h1a = zr + SLF;
    short* h1b = zr + SPAN1 + SLF;
    short* h2a = zr + 2 * SPAN1 + SLF;
    short* h2b = zr + 2 * SPAN1 + SPAN2 + SLF;
    float* c1  = (float*)(zr + 2 * SPAN1 + 2 * SPAN2);
    float* c2  = c1 + H1N;
    float* d1  = c2 + H2N;
    size_t zero_bytes = (size_t)(2 * SPAN1 + 2 * SPAN2) * 2 + (size_t)(H1N + H2N + 160) * 4;

    hipMemsetAsync(zr, 0, zero_bytes, stream);
    convert_x<<<(1327104 + 255) / 256, 256, 0, stream>>>(x, xbf, 1327104);
    transform_w<<<304, 256, 0, stream>>>(W1s, U1s, W2s, U2s, Bt1, Bt2);

    // software pipeline: kernel s runs L1(t=s) and L2(t=s-1)
    for (int s = 0; s <= TT; s++) {
        const short* xt  = xbf + (s < TT ? s : 0) * 6912;
        short*       h1w = (s & 1) ? h1b : h1a;
        const short* h1r = (s & 1) ? h1a : h1b;
        short*       h2w = (s & 1) ? h2a : h2b;
        const short* h2r = (s & 1) ? h2b : h2a;
        fused_step<<<dim3(576), 256, 0, stream>>>(
            xt, h1r, h1w, h2r, h2w, Bt1, Bt2, b1, b2, c1, c2,
            p, s - 1, (int)(s < TT), (int)(s >= 1));
    }

    gemv_kernel<<<dim3(64, 4), 256, 0, stream>>>(p, Wd1, d1);
    final_dense<<<1, 64, 0, stream>>>(d1, bd1, Wd2, bd2, out);
}

// Round 7
// 301.496 us; speedup vs baseline: 11.4875x; 1.3019x over previous
//
#include <hip/hip_runtime.h>
#include <math.h>

// ---------------- problem constants ----------------
#define NB 16
#define TT 12
#define H1 47
#define W1D 46
#define H2 46
#define W2D 44

typedef short short8v __attribute__((ext_vector_type(8)));
typedef float floatx4 __attribute__((ext_vector_type(4)));

__device__ __forceinline__ short f2bf(float x) {
    unsigned u = __float_as_uint(x);
    u = (u + 0x7FFFu + ((u >> 16) & 1u)) >> 16;   // RNE
    return (short)u;
}
__device__ __forceinline__ float bf2f(short s) {
    return __uint_as_float(((unsigned)(unsigned short)s) << 16);
}
__device__ __forceinline__ float hsig(float z) {
    return fminf(fmaxf(0.2f * z + 0.5f, 0.f), 1.f);
}

// ---------------------------------------------------------------------------
__global__ __launch_bounds__(256) void convert_x(const float* __restrict__ x,
                                                 short* __restrict__ xbf, int n) {
    int i = blockIdx.x * 256 + threadIdx.x;
    if (i < n) xbf[i] = f2bf(x[i]);
}

// ---------------------------------------------------------------------------
// Weights -> MFMA B-fragment layout, bf16 (same as R2/R3).
// flat idx = ((c*2+fh)*4+g)*512 + j*32 + ci ; column = g*32+fh*16+j, k = ci
// ---------------------------------------------------------------------------
__global__ __launch_bounds__(256) void transform_w(
    const float* __restrict__ W1s, const float* __restrict__ U1s,
    const float* __restrict__ W2s, const float* __restrict__ U2s,
    short* __restrict__ Bt1, short* __restrict__ Bt2)
{
    int idx = blockIdx.x * 256 + threadIdx.x;       // 0..77823
    int layer2 = idx >= 28672;
    int i = layer2 ? idx - 28672 : idx;
    int ci = i & 31, j = (i >> 5) & 15, g = (i >> 9) & 3, fh = (i >> 11) & 1, c = i >> 12;
    int col = g * 32 + fh * 16 + j;
    float v = 0.f;
    if (!layer2) {
        if (c == 0) {
            if (ci < 18) { int kk = ci / 3, cc = ci - kk * 3; v = W1s[(kk * 3 + cc) * 128 + col]; }
        } else {
            v = U1s[((c - 1) * 32 + ci) * 128 + col];
        }
    } else {
        if (c < 6) v = W2s[(c * 32 + ci) * 128 + col];
        else       v = U2s[((c - 6) * 32 + ci) * 128 + col];
    }
    (layer2 ? Bt2 : Bt1)[i] = f2bf(v);
}

// ---------------------------------------------------------------------------
// One ConvLSTM timestep body. Block = 128 thr = 2 waves (fh halves).
// Tile 4 rows x 16 cols; wave M=64 (4 row-frags), N=64 (4 gates x 16 f).
// A-operands staged in LDS (zeros baked in); K-loop VMEM = B-frags only.
// cst is packed per-thread (private scratch layout).
// ---------------------------------------------------------------------------
template<int LAYER>
__device__ __forceinline__ void step_body(
    const short* __restrict__ xin,     // L1: xbf ; L2: h1 current (bf16)
    const short* __restrict__ hprev,   // recurrent h (bf16)
    const short* __restrict__ Bt,
    const float* __restrict__ bias,
    float* __restrict__ cstp,          // packed: + tid*16 + a*4 + r
    short* __restrict__ hnext,
    short* __restrict__ pool, int t2, int t1,
    int b, int y0, int x0, short* ldsrec, short* ldsaux)
{
    constexpr int Ho   = (LAYER == 1) ? H1 : H2;
    constexpr int Wo   = (LAYER == 1) ? W1D : W2D;
    constexpr int NCH  = (LAYER == 1) ? 7 : 12;
    constexpr int REC0 = (LAYER == 1) ? 1 : 6;
    constexpr int IBS  = (LAYER == 1) ? (TT * 48 * 48 * 3) : (H1 * W1D * 32);
    constexpr int HBS  = Ho * Wo * 32;

    const int tid = threadIdx.x;
    const int lane = tid & 63;
    const int fh = tid >> 6;
    const int tx = lane & 15, q = lane >> 4;
    const short8v z8 = (short8v)0;

    // ---- stage recurrent tile: rows y0..y0+4, cols x0-1..x0+16, SAME-pad zeros ----
    {
        const short* hb0 = hprev + b * HBS;
        for (int i = tid; i < 360; i += 128) {        // 90 pos x 4 chunks(16B)
            int p = i >> 2, c4 = i & 3;
            int row = p / 18, col = p - row * 18;
            int y = y0 + row, x = x0 + col - 1;
            short8v v = z8;
            if (y < Ho && (unsigned)x < (unsigned)Wo)
                v = *(const short8v*)(hb0 + (y * Wo + x) * 32 + c4 * 8);
            *(short8v*)&ldsrec[p * 40 + c4 * 8] = v;
        }
    }

    if (LAYER == 1) {
        // padded im2col of x chunk 0: m=0..63 (4x16 tile), k=kk*3+cc (18 -> pad 32)
        const short* xb0 = xin + b * IBS + t1 * 6912;
        for (int i = tid; i < 64 * 32; i += 128) {
            int m = i >> 5, k = i & 31;
            short v = 0;
            if (k < 18) {
                int kk = k / 3, cc = k - kk * 3;
                int ky = (kk >= 3) ? 1 : 0, kx = kk - ky * 3;
                int ys = y0 + (m >> 4) + ky; if (ys > 47) ys = 47;
                int xs = x0 + (m & 15) + kx; if (xs > 47) xs = 47;
                v = xb0[(ys * 48 + xs) * 3 + cc];
            }
            ldsaux[m * 40 + k] = v;
        }
    } else {
        // stage input-conv source tile: rows y0..y0+4 (clamped), cols x0..x0+17
        // (OOB cols fall in slack; garbage rows feed only masked outputs)
        const short* ib0 = xin + b * IBS;
        for (int i = tid; i < 360; i += 128) {
            int p = i >> 2, c4 = i & 3;
            int row = p / 18, col = p - row * 18;
            int ys = y0 + row; if (ys > H1 - 1) ys = H1 - 1;
            int xs = x0 + col;
            short8v v = *(const short8v*)(ib0 + (ys * W1D + xs) * 32 + c4 * 8);
            *(short8v*)&ldsaux[p * 40 + c4 * 8] = v;
        }
    }
    __syncthreads();

    const short* Btl = Bt + fh * 2048 + tx * 32 + q * 8;
    floatx4 acc[4][4] = {};   // [a(row)][gate]

#pragma unroll
    for (int c = 0; c < NCH; ++c) {
        short8v bf4[4], af[4];
#pragma unroll
        for (int g = 0; g < 4; ++g)
            bf4[g] = *(const short8v*)(Btl + c * 4096 + g * 512);

        if (LAYER == 1 && c == 0) {
#pragma unroll
            for (int a = 0; a < 4; ++a)
                af[a] = *(const short8v*)&ldsaux[(a * 16 + tx) * 40 + q * 8];
        } else if (LAYER == 2 && c < REC0) {
            int ky = (c >= 3) ? 1 : 0, kx = c - ky * 3;
#pragma unroll
            for (int a = 0; a < 4; ++a)
                af[a] = *(const short8v*)&ldsaux[(((a + ky) * 18 + tx + kx)) * 40 + q * 8];
        } else {
            int kk = c - REC0;
            int ky = (kk >= 3) ? 1 : 0, kx = kk - ky * 3;
#pragma unroll
            for (int a = 0; a < 4; ++a)
                af[a] = *(const short8v*)&ldsrec[(((a + ky) * 18 + tx + kx)) * 40 + q * 8];
        }
#pragma unroll
        for (int a = 0; a < 4; ++a)
#pragma unroll
            for (int g = 0; g < 4; ++g)
                acc[a][g] = __builtin_amdgcn_mfma_f32_16x16x32_bf16(af[a], bf4[g], acc[a][g], 0, 0, 0);
    }

    // ---- fused LSTM epilogue (C layout: M=q*4+r -> x, N=tx(+fh*16) -> f) ----
    const int f = fh * 16 + tx;
    const float bi = bias[f], bfv = bias[32 + f], bcv = bias[64 + f], bov = bias[96 + f];
    float* cme = cstp + tid * 16;
    float hv[4][4];
#pragma unroll
    for (int a = 0; a < 4; ++a) {
        int y = y0 + a;
        bool yok = y < Ho;
        floatx4 cold = *(floatx4*)(cme + a * 4);
        floatx4 cnew;
#pragma unroll
        for (int r = 0; r < 4; ++r) {
            int xe = x0 + q * 4 + r;
            float ig = hsig(acc[a][0][r] + bi);
            float fg = hsig(acc[a][1][r] + bfv);
            float gg = fmaxf(acc[a][2][r] + bcv, 0.f);
            float og = hsig(acc[a][3][r] + bov);
            float cn = fg * cold[r] + ig * gg;
            cnew[r] = cn;
            float hn = 0.f;
            if (yok && xe < Wo) {
                short hb = f2bf(og * fmaxf(cn, 0.f));
                hnext[b * HBS + (y * Wo + xe) * 32 + f] = hb;
                hn = bf2f(hb);
            }
            hv[a][r] = hn;
        }
        *(floatx4*)(cme + a * 4) = cnew;
    }

    if (LAYER == 2) {
        // MaxPool(2,2): row pairs (0,1),(2,3); col pairs within r
#pragma unroll
        for (int ap = 0; ap < 2; ++ap) {
            int py = y0 / 2 + ap;
#pragma unroll
            for (int rp = 0; rp < 2; ++rp) {
                int px = x0 / 2 + q * 2 + rp;
                if (py < 23 && px < 22) {
                    float m = fmaxf(fmaxf(hv[2 * ap][2 * rp],     hv[2 * ap][2 * rp + 1]),
                                    fmaxf(hv[2 * ap + 1][2 * rp], hv[2 * ap + 1][2 * rp + 1]));
                    pool[(size_t)b * 194304 + ((t2 * 23 + py) * 22 + px) * 32 + f] = f2bf(m);
                }
            }
        }
    }
}

// ---------------------------------------------------------------------------
// Fused pipeline step. grid = 1152 x 128 thr.
// gid: layer = gid&1 ; b = (gid>>1)&15 ; tile = gid>>5 (0..35)
// ---------------------------------------------------------------------------
__global__ __launch_bounds__(128) void fused_step(
    const short* __restrict__ xbf,
    const short* __restrict__ h1r, short* __restrict__ h1w,
    const short* __restrict__ h2r, short* __restrict__ h2w,
    const short* __restrict__ Bt1, const short* __restrict__ Bt2,
    const float* __restrict__ b1, const float* __restrict__ b2,
    float* __restrict__ c1, float* __restrict__ c2,
    short* __restrict__ pool, int t2, int t1, int do1, int do2)
{
    __shared__ short lds[7200];           // rec [3600] + aux [3600]
    int gid  = blockIdx.x;
    int layer = gid & 1;
    int b     = (gid >> 1) & 15;
    int t36   = gid >> 5;
    int y0 = (t36 / 3) * 4;
    int x0 = (t36 % 3) * 16;

    if (layer == 0) {
        if (!do1) return;
        float* cstp = c1 + (size_t)(b * 36 + t36) * 2048;
        step_body<1>(xbf, h1r, Bt1, b1, cstp, h1w, nullptr, 0, t1,
                     b, y0, x0, lds, lds + 3600);
    } else {
        if (!do2) return;
        float* cstp = c2 + (size_t)(b * 36 + t36) * 2048;
        step_body<2>(h1r, h2r, Bt2, b2, cstp, h2w, pool, t2, 0,
                     b, y0, x0, lds, lds + 3600);
    }
}

// ---------------------------------------------------------------------------
__global__ __launch_bounds__(256) void gemv_kernel(
    const short* __restrict__ p, const float* __restrict__ Wd1, float* __restrict__ d1)
{
    int by = blockIdx.y;                 // batch group: 4*by .. 4*by+3
    int k0 = blockIdx.x * 3036;          // 194304 / 64
    float part[4][10];
#pragma unroll
    for (int bb = 0; bb < 4; bb++)
#pragma unroll
        for (int j = 0; j < 10; j++) part[bb][j] = 0.f;

    for (int k = k0 + threadIdx.x; k < k0 + 3036; k += 256) {
        const float* wr = Wd1 + (size_t)k * 10;
        float wv[10];
#pragma unroll
        for (int j = 0; j < 10; j++) wv[j] = wr[j];
#pragma unroll
        for (int bb = 0; bb < 4; bb++) {
            float m = bf2f(p[(size_t)(by * 4 + bb) * 194304 + k]);
#pragma unroll
            for (int j = 0; j < 10; j++) part[bb][j] = fmaf(m, wv[j], part[bb][j]);
        }
    }
    __shared__ float red[4][10][4];
    int lane = threadIdx.x & 63, wv2 = threadIdx.x >> 6;
#pragma unroll
    for (int bb = 0; bb < 4; bb++)
#pragma unroll
        for (int j = 0; j < 10; j++) {
            float v = part[bb][j];
            for (int off = 32; off > 0; off >>= 1) v += __shfl_down(v, off);
            if (lane == 0) red[bb][j][wv2] = v;
        }
    __syncthreads();
    if (threadIdx.x < 40) {
        int bb = threadIdx.x / 10, j = threadIdx.x % 10;
        float s = red[bb][j][0] + red[bb][j][1] + red[bb][j][2] + red[bb][j][3];
        atomicAdd(&d1[(by * 4 + bb) * 10 + j], s);
    }
}

__global__ void final_dense(const float* __restrict__ d1, const float* __restrict__ bd1,
                            const float* __restrict__ Wd2, const float* __restrict__ bd2,
                            float* __restrict__ out)
{
    int b = threadIdx.x;
    if (b < NB) {
        float s = bd2[0];
#pragma unroll
        for (int j = 0; j < 10; j++) s += (d1[b * 10 + j] + bd1[j]) * Wd2[j];
        out[b] = s;
    }
}

// ---------------------------------------------------------------------------
extern "C" void kernel_launch(void* const* d_in, const int* in_sizes, int n_in,
                              void* d_out, int out_size, void* d_ws, size_t ws_size,
                              hipStream_t stream)
{
    const float* x   = (const float*)d_in[0];
    const float* W1s = (const float*)d_in[1];
    const float* U1s = (const float*)d_in[2];
    const float* b1  = (const float*)d_in[3];
    const float* W2s = (const float*)d_in[4];
    const float* U2s = (const float*)d_in[5];
    const float* b2  = (const float*)d_in[6];
    const float* Wd1 = (const float*)d_in[7];
    const float* bd1 = (const float*)d_in[8];
    const float* Wd2 = (const float*)d_in[9];
    const float* bd2 = (const float*)d_in[10];
    float* out = (float*)d_out;

    const int H1N = NB * H1 * W1D * 32;   // 1106944
    const int H2N = NB * H2 * W2D * 32;   // 1036288
    const int SLF = 32, SLB = 8192;
    const int SPAN1 = SLF + H1N + SLB;
    const int SPAN2 = SLF + H2N + SLB;
    const int CPL   = 16 * 36 * 2048;     // packed cst floats per layer = 1179648

    short* Bt1 = (short*)d_ws;            // 28672
    short* Bt2 = Bt1 + 28672;             // 49152
    short* xbf = Bt2 + 49152;             // 1327104
    short* p   = xbf + 1327104;           // 3108864
    short* zr  = p + 3108864;             // ---- zero region ----
    short* h1a = zr + SLF;
    short* h1b = zr + SPAN1 + SLF;
    short* h2a = zr + 2 * SPAN1 + SLF;
    short* h2b = zr + 2 * SPAN1 + SPAN2 + SLF;
    float* c1  = (float*)(zr + 2 * SPAN1 + 2 * SPAN2);
    float* c2  = c1 + CPL;
    float* d1  = c2 + CPL;
    size_t zero_bytes = (size_t)(2 * SPAN1 + 2 * SPAN2) * 2 + (size_t)(2 * CPL + 160) * 4;

    hipMemsetAsync(zr, 0, zero_bytes, stream);
    convert_x<<<(1327104 + 255) / 256, 256, 0, stream>>>(x, xbf, 1327104);
    transform_w<<<304, 256, 0, stream>>>(W1s, U1s, W2s, U2s, Bt1, Bt2);

    // software pipeline: kernel s runs L1(t=s) and L2(t=s-1)
    for (int s = 0; s <= TT; s++) {
        short*       h1w = (s & 1) ? h1b : h1a;
        const short* h1r = (s & 1) ? h1a : h1b;
        short*       h2w = (s & 1) ? h2a : h2b;
        const short* h2r = (s & 1) ? h2b : h2a;
        fused_step<<<dim3(1152), 128, 0, stream>>>(
            xbf, h1r, h1w, h2r, h2w, Bt1, Bt2, b1, b2, c1, c2,
            p, s - 1, (s < TT ? s : 0), (int)(s < TT), (int)(s >= 1));
    }

    gemv_kernel<<<dim3(64, 4), 256, 0, stream>>>(p, Wd1, d1);
    final_dense<<<1, 64, 0, stream>>>(d1, bd1, Wd2, bd2, out);
}